// Round 14
// baseline (427.021 us; speedup 1.0000x reference)
//
#include <hip/hip_runtime.h>
#include <hip/hip_bf16.h>

typedef __attribute__((ext_vector_type(8))) short short8;
typedef __attribute__((ext_vector_type(4))) float f32x4;
typedef __attribute__((ext_vector_type(2))) float floatx2;
typedef __attribute__((ext_vector_type(4))) unsigned uintx4;
typedef __attribute__((ext_vector_type(2))) unsigned uintx2;

namespace {

constexpr int kNV = 160000;
constexpr int kNE = 480000;
constexpr int kB  = 16;
constexpr int kV  = 10000;
constexpr int kScanBlocks = kNV / 256;  // 625, exact
constexpr int kMaxAdjPad = 2 * kNE + 3 * kNV;  // 1,440,000 worst case

__device__ inline unsigned short f2b(float f) {  // fp32 -> bf16 RNE
  unsigned u = __float_as_uint(f);
  unsigned r = u + 0x7fffu + ((u >> 16) & 1u);
  return (unsigned short)(r >> 16);
}
__device__ inline unsigned pk2(float lo, float hi) {
  return ((unsigned)f2b(hi) << 16) | (unsigned)f2b(lo);
}
// fp32 -> OCP e4m3 via HW converter (RNE, saturating)
__device__ inline unsigned char f2q(float f) {
  int r = __builtin_amdgcn_cvt_pk_fp8_f32(f, 0.f, 0, false);
  return (unsigned char)(r & 0xff);
}

// ---------------- CSR build (degree-padded to multiples of 4) ----------------

__global__ __launch_bounds__(256) void count_deg_kernel(const int2* __restrict__ edges,
                                                        int* __restrict__ deg) {
  int i = blockIdx.x * 256 + threadIdx.x;
  if (i < kNE) {
    int2 e = edges[i];
    atomicAdd(&deg[e.x], 1);
    atomicAdd(&deg[e.y], 1);
  }
}

__global__ __launch_bounds__(256) void block_sum_kernel(const int* __restrict__ deg,
                                                        int* __restrict__ bsum) {
  const int tid = threadIdx.x;
  int v = (deg[blockIdx.x * 256 + tid] + 3) & ~3;
  for (int off = 32; off > 0; off >>= 1) v += __shfl_down(v, off);
  __shared__ int ws[4];
  if ((tid & 63) == 0) ws[tid >> 6] = v;
  __syncthreads();
  if (tid == 0) bsum[blockIdx.x] = ws[0] + ws[1] + ws[2] + ws[3];
}

__global__ __launch_bounds__(1024) void scan_bsum_kernel(const int* __restrict__ bsum,
                                                         int* __restrict__ boff,
                                                         int* __restrict__ total_out) {
  __shared__ int s[1024];
  const int t = threadIdx.x;
  int v = (t < kScanBlocks) ? bsum[t] : 0;
  s[t] = v;
  __syncthreads();
  for (int off = 1; off < 1024; off <<= 1) {
    int u = (t >= off) ? s[t - off] : 0;
    __syncthreads();
    s[t] += u;
    __syncthreads();
  }
  if (t < kScanBlocks) boff[t] = s[t] - v;
  if (t == kScanBlocks - 1) total_out[0] = s[t];
}

// Pass 3: rowptr/cursor + packed rowinfo {beg/4, (deg<<8)|nq}.
__global__ __launch_bounds__(256) void write_rowptr_kernel(const int* __restrict__ deg,
                                                           const int* __restrict__ boff,
                                                           int* __restrict__ rowptr,
                                                           int* __restrict__ cursor,
                                                           int2* __restrict__ rowinfo) {
  __shared__ int s[256];
  const int tid = threadIdx.x;
  const int i = blockIdx.x * 256 + tid;
  const int d = deg[i];
  int v = (d + 3) & ~3;
  s[tid] = v;
  __syncthreads();
  for (int off = 1; off < 256; off <<= 1) {
    int u = (tid >= off) ? s[tid - off] : 0;
    __syncthreads();
    s[tid] += u;
    __syncthreads();
  }
  int excl = s[tid] - v + boff[blockIdx.x];
  rowptr[i] = excl;
  cursor[i] = excl;
  rowinfo[i] = make_int2(excl >> 2, (d << 8) | (v >> 2));
}

__global__ __launch_bounds__(256) void fill_adj_kernel(const int2* __restrict__ edges,
                                                       int* __restrict__ cursor,
                                                       int* __restrict__ adj) {
  int i = blockIdx.x * 256 + threadIdx.x;
  if (i < kNE) {
    int2 e = edges[i];
    int p = atomicAdd(&cursor[e.x], 1);
    adj[p] = e.y;
    int q = atomicAdd(&cursor[e.y], 1);
    adj[q] = e.x;
  }
}

__global__ __launch_bounds__(256) void pad_adj_kernel(const int* __restrict__ deg,
                                                      const int* __restrict__ rowptr,
                                                      int* __restrict__ adj) {
  int v = blockIdx.x * 256 + threadIdx.x;
  if (v < kNV) {
    int e = rowptr[v] + deg[v];
    int e2 = rowptr[v + 1];
    for (int p = e; p < e2; ++p) adj[p] = kNV;
  }
}

// ------- Weight prep (bf16): MFMA-fragment-swizzled concat [W0|W1] ---------

__global__ __launch_bounds__(256) void prep_wswz_kernel(const float* __restrict__ w0,
                                                        const float* __restrict__ w1,
                                                        unsigned short* __restrict__ dst,
                                                        int din) {
  const int K = 2 * din;
  const int total = (K / 32) * 16 * 64;
  int g = blockIdx.x * 256 + threadIdx.x;
  if (g >= total) return;
  int lane = g & 63;
  int cb = (g >> 6) & 15;
  int s = g >> 10;
  int ch = cb * 16 + (lane & 15);
  int kb = s * 32 + (lane >> 4) * 8;
  unsigned short v[8];
#pragma unroll
  for (int j = 0; j < 8; ++j) {
    int k = kb + j;
    float f = (k < din) ? w0[(size_t)ch * din + k] : w1[(size_t)ch * din + (k - din)];
    v[j] = f2b(f);
  }
  uint4 pk;
  pk.x = (unsigned)v[0] | ((unsigned)v[1] << 16);
  pk.y = (unsigned)v[2] | ((unsigned)v[3] << 16);
  pk.z = (unsigned)v[4] | ((unsigned)v[5] << 16);
  pk.w = (unsigned)v[6] | ((unsigned)v[7] << 16);
  *(uint4*)(dst + (size_t)g * 8) = pk;
}

// ------- Weight prep (fp8): W0 half as fp8 B-frags, same fragment layout ----

__global__ __launch_bounds__(256) void prep_wswz_fp8_kernel(const float* __restrict__ w0,
                                                            unsigned char* __restrict__ dst,
                                                            int din) {
  const int total = (din / 32) * 16 * 64;
  int g = blockIdx.x * 256 + threadIdx.x;
  if (g >= total) return;
  int lane = g & 63;
  int cb = (g >> 6) & 15;
  int s = g >> 10;
  int ch = cb * 16 + (lane & 15);
  int kb = s * 32 + (lane >> 4) * 8;
  float f[8];
#pragma unroll
  for (int j = 0; j < 8; ++j) f[j] = w0[(size_t)ch * din + kb + j];
  int r0 = 0, r1 = 0;
  r0 = __builtin_amdgcn_cvt_pk_fp8_f32(f[0], f[1], r0, false);
  r0 = __builtin_amdgcn_cvt_pk_fp8_f32(f[2], f[3], r0, true);
  r1 = __builtin_amdgcn_cvt_pk_fp8_f32(f[4], f[5], r1, false);
  r1 = __builtin_amdgcn_cvt_pk_fp8_f32(f[6], f[7], r1, true);
  uintx2 pk;
  pk.x = (unsigned)r0;
  pk.y = (unsigned)r1;
  *(uintx2*)(dst + (size_t)g * 8) = pk;
}

// ------ Layer 0: din=3 -> dout=128; emits fp8 x1q only (coalesced) ----------

__global__ __launch_bounds__(256) void gcn_layer0_kernel(
    const float* __restrict__ x, const int* __restrict__ rowptr,
    const int* __restrict__ deg, const int* __restrict__ adj,
    const float* __restrict__ w0, const float* __restrict__ b0,
    const float* __restrict__ w1, const float* __restrict__ b1,
    unsigned char* __restrict__ yq) {
  constexpr int TM = 256, DOUT = 128;
  __shared__ __align__(16) float xa[TM][8];  // [0..2] self, [3..5] agg, [6] deg
  const int v0 = blockIdx.x * TM;
  const int tid = threadIdx.x;

  {
    const int v = v0 + tid;
    const float s0 = x[(size_t)v * 3 + 0];
    const float s1 = x[(size_t)v * 3 + 1];
    const float s2 = x[(size_t)v * 3 + 2];
    const int beg = rowptr[v];
    const int n = deg[v];
    float a0 = 0.f, a1 = 0.f, a2 = 0.f;
    int j = beg;
    const int e = beg + n;
    for (; j + 4 <= e; j += 4) {
      int u0 = adj[j], u1 = adj[j + 1], u2 = adj[j + 2], u3 = adj[j + 3];
      float p0 = x[(size_t)u0 * 3], p1 = x[(size_t)u0 * 3 + 1], p2 = x[(size_t)u0 * 3 + 2];
      float q0 = x[(size_t)u1 * 3], q1 = x[(size_t)u1 * 3 + 1], q2 = x[(size_t)u1 * 3 + 2];
      float r0 = x[(size_t)u2 * 3], r1 = x[(size_t)u2 * 3 + 1], r2 = x[(size_t)u2 * 3 + 2];
      float t0 = x[(size_t)u3 * 3], t1 = x[(size_t)u3 * 3 + 1], t2 = x[(size_t)u3 * 3 + 2];
      a0 += (p0 + q0) + (r0 + t0);
      a1 += (p1 + q1) + (r1 + t1);
      a2 += (p2 + q2) + (r2 + t2);
    }
    for (; j < e; ++j) {
      int u = adj[j];
      a0 += x[(size_t)u * 3 + 0];
      a1 += x[(size_t)u * 3 + 1];
      a2 += x[(size_t)u * 3 + 2];
    }
    xa[tid][0] = s0;
    xa[tid][1] = s1;
    xa[tid][2] = s2;
    xa[tid][3] = a0;
    xa[tid][4] = a1;
    xa[tid][5] = a2;
    xa[tid][6] = (float)n;
    xa[tid][7] = 0.f;
  }
  __syncthreads();

  const int o = tid & 127;
  const int half = tid >> 7;
  const float w00 = w0[o * 3], w01 = w0[o * 3 + 1], w02 = w0[o * 3 + 2];
  const float w10 = w1[o * 3], w11 = w1[o * 3 + 1], w12 = w1[o * 3 + 2];
  const float bb0 = b0[o], bb1 = b1[o];
  for (int m = half; m < TM; m += 2) {
    float4 lo = *(const float4*)&xa[m][0];
    float4 hi = *(const float4*)&xa[m][4];
    float r = bb0 + hi.z * bb1
            + lo.x * w00 + lo.y * w01 + lo.z * w02
            + lo.w * w10 + hi.x * w11 + hi.y * w12;
    yq[(size_t)(v0 + m) * DOUT + o] = f2q(fmaxf(r, 0.f));
  }
}

// ---------------- Fused GCN layer via MFMA (fp8 self+gather) ----------------
// Gather: dual-row half-wave pairs, SOFTWARE-PIPELINED 1-deep at pair level —
// pair p+1's rowinfo/indices/first-rows issue before pair p is consumed
// (~9 loads in flight vs 4; hides the per-pair cold-start latency).
// rowinfo packs {beg/4, deg<<8|nq}: one 8B load replaces 3 index-path loads.
// Pass 0: fp8_fp8 MFMA (raw fp8 self rows + fp8 W0 frags). Pass 1: bf16 MFMA
// (agg tile from LDS + bf16 W1 frags). l1 output: fp8 via swizzled LDS pack.

template <int DIN, bool POOL>
__device__ __forceinline__ void gcn_mfma_body(
    const unsigned char* __restrict__ xq,
    const int2* __restrict__ rowinfo,
    const int* __restrict__ adj, const unsigned short* __restrict__ wswz,
    const unsigned char* __restrict__ wq,
    const float* __restrict__ b0, const float* __restrict__ b1,
    void* __restrict__ out) {
  constexpr int TM = 32;
  constexpr int ROWB = DIN * 2;  // bytes per LDS agg row (bf16)
  __shared__ __align__(16) char lds[TM * ROWB];
  __shared__ float degs_s[TM];

  const int tid = threadIdx.x;
  const int lane = tid & 63;
  const int wave = tid >> 6;
  const int half = lane >> 5;  // row-pair selector
  const int hl = lane & 31;    // position within row

  int v0, valid, batch;
  if constexpr (POOL) {
    batch = blockIdx.y;
    v0 = batch * kV + blockIdx.x * TM;
    valid = min(TM, kV - (int)blockIdx.x * TM);
  } else {
    batch = 0;
    v0 = blockIdx.x * TM;
    valid = TM;
  }

  auto swz = [&](int row, int off) { return row * ROWB + (off ^ ((row & 7) << 4)); };

  const int4* adjq = reinterpret_cast<const int4*>(adj);
  const int4 Z4 = make_int4(kNV, kNV, kNV, kNV);

  // pair-state loader: rowinfo + both index quads
  auto load_pair = [&](int pr, int& m, int& nq, int& nqm, int& q0,
                       int4& i0, int4& i1) {
    m = wave * 8 + pr * 2 + half;
    const bool live = m < valid;
    int2 ri = rowinfo[live ? (v0 + m) : v0];
    q0 = ri.x;
    nq = live ? (ri.y & 0xff) : 0;
    if (hl == 0) degs_s[m] = live ? (float)(ri.y >> 8) : 0.f;
    nqm = max(nq, __shfl_xor(nq, 32));
    i0 = (nq > 0) ? adjq[q0] : Z4;
    i1 = (nq > 1) ? adjq[q0 + 1] : Z4;
  };

  if constexpr (DIN == 256) {
    const uintx2* xr = reinterpret_cast<const uintx2*>(xq);  // row = 32 uintx2
    // prologue: pair 0
    int mA, nqA, nqmA, q0A;
    int4 i0A, i1A;
    load_pair(0, mA, nqA, nqmA, q0A, i0A, i1A);
    uintx2 cA0 = xr[(size_t)i0A.x * 32 + hl];
    uintx2 cA1 = xr[(size_t)i0A.y * 32 + hl];
    uintx2 cA2 = xr[(size_t)i0A.z * 32 + hl];
    uintx2 cA3 = xr[(size_t)i0A.w * 32 + hl];
#pragma unroll
    for (int pr = 0; pr < 4; ++pr) {
      // prefetch pair pr+1 (issued before consuming pair pr)
      int mB = 0, nqB = 0, nqmB = 0, q0B = 0;
      int4 i0B = Z4, i1B = Z4;
      uintx2 cB0 = {}, cB1 = {}, cB2 = {}, cB3 = {};
      if (pr < 3) {
        load_pair(pr + 1, mB, nqB, nqmB, q0B, i0B, i1B);
        cB0 = xr[(size_t)i0B.x * 32 + hl];
        cB1 = xr[(size_t)i0B.y * 32 + hl];
        cB2 = xr[(size_t)i0B.z * 32 + hl];
        cB3 = xr[(size_t)i0B.w * 32 + hl];
      }
      // consume current pair
      float r0 = 0, r1 = 0, r2 = 0, r3 = 0, r4 = 0, r5 = 0, r6 = 0, r7 = 0;
#define ACCQ8(c) do { \
    floatx2 f0 = __builtin_amdgcn_cvt_pk_f32_fp8((int)(c).x, false); \
    floatx2 f1 = __builtin_amdgcn_cvt_pk_f32_fp8((int)(c).x, true); \
    floatx2 f2 = __builtin_amdgcn_cvt_pk_f32_fp8((int)(c).y, false); \
    floatx2 f3 = __builtin_amdgcn_cvt_pk_f32_fp8((int)(c).y, true); \
    r0 += f0.x; r1 += f0.y; r2 += f1.x; r3 += f1.y; \
    r4 += f2.x; r5 += f2.y; r6 += f3.x; r7 += f3.y; } while (0)
      int4 inext = i1A;
      for (int t = 1; t < nqmA; ++t) {
        uintx2 n0 = xr[(size_t)inext.x * 32 + hl];
        uintx2 n1 = xr[(size_t)inext.y * 32 + hl];
        uintx2 n2 = xr[(size_t)inext.z * 32 + hl];
        uintx2 n3 = xr[(size_t)inext.w * 32 + hl];
        inext = (t + 1 < nqA) ? adjq[q0A + t + 1] : Z4;
        ACCQ8(cA0); ACCQ8(cA1); ACCQ8(cA2); ACCQ8(cA3);
        cA0 = n0; cA1 = n1; cA2 = n2; cA3 = n3;
      }
      ACCQ8(cA0); ACCQ8(cA1); ACCQ8(cA2); ACCQ8(cA3);
#undef ACCQ8
      uintx4 pk;
      pk.x = pk2(r0, r1);
      pk.y = pk2(r2, r3);
      pk.z = pk2(r4, r5);
      pk.w = pk2(r6, r7);
      *(uintx4*)(lds + swz(mA, hl * 16)) = pk;
      // rotate
      mA = mB; nqA = nqB; nqmA = nqmB; q0A = q0B; i1A = i1B;
      cA0 = cB0; cA1 = cB1; cA2 = cB2; cA3 = cB3;
    }
  } else {  // DIN == 128
    const unsigned* xr = reinterpret_cast<const unsigned*>(xq);  // row = 32 uints
    int mA, nqA, nqmA, q0A;
    int4 i0A, i1A;
    load_pair(0, mA, nqA, nqmA, q0A, i0A, i1A);
    unsigned cA0 = xr[(size_t)i0A.x * 32 + hl];
    unsigned cA1 = xr[(size_t)i0A.y * 32 + hl];
    unsigned cA2 = xr[(size_t)i0A.z * 32 + hl];
    unsigned cA3 = xr[(size_t)i0A.w * 32 + hl];
#pragma unroll
    for (int pr = 0; pr < 4; ++pr) {
      int mB = 0, nqB = 0, nqmB = 0, q0B = 0;
      int4 i0B = Z4, i1B = Z4;
      unsigned cB0 = 0, cB1 = 0, cB2 = 0, cB3 = 0;
      if (pr < 3) {
        load_pair(pr + 1, mB, nqB, nqmB, q0B, i0B, i1B);
        cB0 = xr[(size_t)i0B.x * 32 + hl];
        cB1 = xr[(size_t)i0B.y * 32 + hl];
        cB2 = xr[(size_t)i0B.z * 32 + hl];
        cB3 = xr[(size_t)i0B.w * 32 + hl];
      }
      float r0 = 0, r1 = 0, r2 = 0, r3 = 0;
#define ACCQ4(c) do { \
    floatx2 f0 = __builtin_amdgcn_cvt_pk_f32_fp8((int)(c), false); \
    floatx2 f1 = __builtin_amdgcn_cvt_pk_f32_fp8((int)(c), true); \
    r0 += f0.x; r1 += f0.y; r2 += f1.x; r3 += f1.y; } while (0)
      int4 inext = i1A;
      for (int t = 1; t < nqmA; ++t) {
        unsigned n0 = xr[(size_t)inext.x * 32 + hl];
        unsigned n1 = xr[(size_t)inext.y * 32 + hl];
        unsigned n2 = xr[(size_t)inext.z * 32 + hl];
        unsigned n3 = xr[(size_t)inext.w * 32 + hl];
        inext = (t + 1 < nqA) ? adjq[q0A + t + 1] : Z4;
        ACCQ4(cA0); ACCQ4(cA1); ACCQ4(cA2); ACCQ4(cA3);
        cA0 = n0; cA1 = n1; cA2 = n2; cA3 = n3;
      }
      ACCQ4(cA0); ACCQ4(cA1); ACCQ4(cA2); ACCQ4(cA3);
#undef ACCQ4
      uintx2 pk;
      pk.x = pk2(r0, r1);
      pk.y = pk2(r2, r3);
      *(uintx2*)(lds + swz(mA, hl * 8)) = pk;
      mA = mB; nqA = nqB; nqmA = nqmB; q0A = q0B; i1A = i1B;
      cA0 = cB0; cA1 = cB1; cA2 = cB2; cA3 = cB3;
    }
  }

  // ---- MFMA: wave -> channels [wave*64, wave*64+64) ----
  const int col = lane & 15;
  const int kgrp = lane >> 4;
  const int cbw = wave * 4;  // channel-block base (16-ch blocks)
  f32x4 acc[2][4] = {};

  // pass 0: fp8 self rows from global + fp8 W0 frags (same frag k-layout)
  const long* wql = reinterpret_cast<const long*>(wq);
  for (int s = 0; s < DIN / 32; ++s) {
    const int ke = s * 32 + kgrp * 8;
    long a0 = 0, a1 = 0;
    if constexpr (POOL) {
      if (col < valid)      a0 = *(const long*)(xq + (size_t)(v0 + col) * DIN + ke);
      if (col + 16 < valid) a1 = *(const long*)(xq + (size_t)(v0 + col + 16) * DIN + ke);
    } else {
      a0 = *(const long*)(xq + (size_t)(v0 + col) * DIN + ke);
      a1 = *(const long*)(xq + (size_t)(v0 + col + 16) * DIN + ke);
    }
#pragma unroll
    for (int nf = 0; nf < 4; ++nf) {
      long bq = wql[((size_t)(s * 16 + cbw + nf)) * 64 + lane];
      acc[0][nf] = __builtin_amdgcn_mfma_f32_16x16x32_fp8_fp8(a0, bq, acc[0][nf], 0, 0, 0);
      acc[1][nf] = __builtin_amdgcn_mfma_f32_16x16x32_fp8_fp8(a1, bq, acc[1][nf], 0, 0, 0);
    }
  }

  __syncthreads();

  // pass 1: agg rows from LDS (bf16), W1 half of bf16 wswz (s2 + DIN/32)
  for (int s2 = 0; s2 < DIN / 32; ++s2) {
    const int kb = (s2 * 32 + kgrp * 8) * 2;
    short8 a0 = *(const short8*)(lds + swz(col, kb));
    short8 a1 = *(const short8*)(lds + swz(col + 16, kb));
    const unsigned short* wb =
        wswz + ((size_t)((DIN / 32 + s2) * 16 + cbw) * 64 + lane) * 8;
#pragma unroll
    for (int nf = 0; nf < 4; ++nf) {
      short8 bfrag = *(const short8*)(wb + (size_t)nf * 512);
      acc[0][nf] = __builtin_amdgcn_mfma_f32_16x16x32_bf16(a0, bfrag, acc[0][nf], 0, 0, 0);
      acc[1][nf] = __builtin_amdgcn_mfma_f32_16x16x32_bf16(a1, bfrag, acc[1][nf], 0, 0, 0);
    }
  }

  // ---- epilogue: C/D map col=lane&15, row=(lane>>4)*4+reg (+16 for mf=1) ----
  const int rb = kgrp * 4;
  const int obase = wave * 64;
  if constexpr (POOL) {
    float* part = (float*)out;  // [kB][16][256] partial slots
    const int slot = blockIdx.x & 15;
#pragma unroll
    for (int nf = 0; nf < 4; ++nf) {
      int o = obase + nf * 16 + col;
      float bb0 = b0[o], bb1 = b1[o];
      float s = 0.f;
#pragma unroll
      for (int mf = 0; mf < 2; ++mf)
#pragma unroll
        for (int j = 0; j < 4; ++j) {
          int row = mf * 16 + rb + j;
          if (row < valid)
            s += fmaxf(acc[mf][nf][j] + bb0 + degs_s[row] * bb1, 0.f);
        }
      s += __shfl_xor(s, 16);
      s += __shfl_xor(s, 32);
      if (lane < 16)
        atomicAdd(&part[((size_t)batch * 16 + slot) * 256 + o], s * (1.0f / (float)kV));
    }
  } else {
    // fp8 output: pack into (consumed) LDS agg tile with 16B XOR swizzle,
    // then stream as coalesced 16B stores (TM*ROWB == 32*256 for DIN=128).
    __syncthreads();  // all waves done reading agg tile
    unsigned char* packb = (unsigned char*)lds;
#pragma unroll
    for (int nf = 0; nf < 4; ++nf) {
      int o = obase + nf * 16 + col;
      float bb0 = b0[o], bb1 = b1[o];
#pragma unroll
      for (int mf = 0; mf < 2; ++mf)
#pragma unroll
        for (int j = 0; j < 4; ++j) {
          int row = mf * 16 + rb + j;
          float val = fmaxf(acc[mf][nf][j] + bb0 + degs_s[row] * bb1, 0.f);
          packb[row * 256 + (o ^ ((row & 15) << 4))] = f2q(val);
        }
    }
    __syncthreads();
    unsigned char* xqo = (unsigned char*)out;
    const int row = tid >> 3;        // 0..31
    const int o0 = (tid & 7) * 32;   // 32B per thread
    const int xsw = (row & 15) << 4;
    uintx4 d0 = *(const uintx4*)(lds + row * 256 + (o0 ^ xsw));
    uintx4 d1 = *(const uintx4*)(lds + row * 256 + ((o0 + 16) ^ xsw));
    *(uintx4*)(xqo + (size_t)(v0 + row) * 256 + o0) = d0;
    *(uintx4*)(xqo + (size_t)(v0 + row) * 256 + o0 + 16) = d1;
  }
}

__global__ __launch_bounds__(256, 8) void gcn_l1_kernel(
    const unsigned char* __restrict__ xq, const int2* __restrict__ rowinfo,
    const int* __restrict__ adj, const unsigned short* __restrict__ wswz,
    const unsigned char* __restrict__ wq,
    const float* __restrict__ b0, const float* __restrict__ b1,
    void* __restrict__ out) {
  gcn_mfma_body<128, false>(xq, rowinfo, adj, wswz, wq, b0, b1, out);
}

__global__ __launch_bounds__(256, 8) void gcn_l2pool_kernel(
    const unsigned char* __restrict__ xq, const int2* __restrict__ rowinfo,
    const int* __restrict__ adj, const unsigned short* __restrict__ wswz,
    const unsigned char* __restrict__ wq,
    const float* __restrict__ b0, const float* __restrict__ b1,
    void* __restrict__ out) {
  gcn_mfma_body<256, true>(xq, rowinfo, adj, wswz, wq, b0, b1, out);
}

// Sum the 16 partial slots per batch into pooled[b][o].
__global__ __launch_bounds__(256) void pool_reduce_kernel(const float* __restrict__ part,
                                                          float* __restrict__ pooled) {
  const int b = blockIdx.x;
  const int o = threadIdx.x;
  float s = 0.f;
#pragma unroll
  for (int k = 0; k < 16; ++k) s += part[((size_t)b * 16 + k) * 256 + o];
  pooled[b * 256 + o] = s;
}

// ---------------- MLP head ----------------

__global__ __launch_bounds__(256) void fc1_kernel(const float* __restrict__ pooled,
                                                  const float* __restrict__ w,
                                                  const float* __restrict__ b,
                                                  float* __restrict__ h) {
  __shared__ float ps[256];
  const int bb = blockIdx.x;
  const int o = blockIdx.y * 256 + threadIdx.x;
  ps[threadIdx.x] = pooled[bb * 256 + threadIdx.x];
  __syncthreads();
  const float4* wr = reinterpret_cast<const float4*>(w + (size_t)o * 256);
  float acc = b[o];
  for (int d4 = 0; d4 < 64; ++d4) {
    float4 wv = wr[d4];
    acc += ps[d4 * 4 + 0] * wv.x + ps[d4 * 4 + 1] * wv.y
         + ps[d4 * 4 + 2] * wv.z + ps[d4 * 4 + 3] * wv.w;
  }
  h[bb * 1024 + o] = fmaxf(acc, 0.f);
}

__global__ __launch_bounds__(64) void fc2_kernel(const float* __restrict__ h,
                                                 const float* __restrict__ w,
                                                 const float* __restrict__ b,
                                                 float* __restrict__ out) {
  const int t = blockIdx.x;  // 0..159
  const int bb = t / 10, c = t % 10;
  const int lane = threadIdx.x;
  const float* hr = h + bb * 1024;
  const float* wr = w + c * 1024;
  float acc = 0.f;
#pragma unroll
  for (int k = 0; k < 16; ++k) acc += hr[k * 64 + lane] * wr[k * 64 + lane];
#pragma unroll
  for (int off = 32; off > 0; off >>= 1) acc += __shfl_xor(acc, off);
  if (lane == 0) out[t] = acc + b[c];
}

}  // namespace

extern "C" void kernel_launch(void* const* d_in, const int* in_sizes, int n_in,
                              void* d_out, int out_size, void* d_ws, size_t ws_size,
                              hipStream_t stream) {
  const float* verts = (const float*)d_in[0];
  const int2*  edges = (const int2*)d_in[1];
  const float* g0w0 = (const float*)d_in[2];
  const float* g0b0 = (const float*)d_in[3];
  const float* g0w1 = (const float*)d_in[4];
  const float* g0b1 = (const float*)d_in[5];
  const float* g1w0 = (const float*)d_in[6];
  const float* g1b0 = (const float*)d_in[7];
  const float* g1w1 = (const float*)d_in[8];
  const float* g1b1 = (const float*)d_in[9];
  const float* g2w0 = (const float*)d_in[10];
  const float* g2b0 = (const float*)d_in[11];
  const float* g2w1 = (const float*)d_in[12];
  const float* g2b1 = (const float*)d_in[13];
  const float* fc1w = (const float*)d_in[14];
  const float* fc1b = (const float*)d_in[15];
  const float* fc2w = (const float*)d_in[16];
  const float* fc2b = (const float*)d_in[17];
  float* outp = (float*)d_out;

  char* p = (char*)d_ws;
  auto alloc = [&](size_t bytes) {
    char* r = p;
    p += (bytes + 255) & ~(size_t)255;
    return r;
  };
  unsigned char*  x1q  = (unsigned char*)alloc((size_t)(kNV + 1) * 128);   // fp8, +zero row
  unsigned char*  x2q  = (unsigned char*)alloc((size_t)(kNV + 1) * 256);   // fp8, +zero row
  unsigned short* ws1  = (unsigned short*)alloc((size_t)256 * 256 * 2);    // bf16 [W0|W1]
  unsigned short* ws2  = (unsigned short*)alloc((size_t)256 * 512 * 2);
  unsigned char*  ws1q = (unsigned char*)alloc((size_t)(128 / 32) * 16 * 64 * 8);  // fp8 W0
  unsigned char*  ws2q = (unsigned char*)alloc((size_t)(256 / 32) * 16 * 64 * 8);
  int*   deg    = (int*)alloc((size_t)kNV * sizeof(int));
  int*   rowptr = (int*)alloc((size_t)(kNV + 1) * sizeof(int));
  int*   cursor = (int*)alloc((size_t)kNV * sizeof(int));
  int2*  rowinfo = (int2*)alloc((size_t)kNV * sizeof(int2));
  int*   adj    = (int*)alloc((size_t)kMaxAdjPad * sizeof(int));
  int*   bsum   = (int*)alloc((size_t)kScanBlocks * sizeof(int));
  int*   boff   = (int*)alloc((size_t)kScanBlocks * sizeof(int));
  float* part   = (float*)alloc((size_t)kB * 16 * 256 * sizeof(float));
  float* pooled = (float*)alloc((size_t)kB * 256 * sizeof(float));
  float* h      = (float*)alloc((size_t)kB * 1024 * sizeof(float));

  (void)hipMemsetAsync(deg, 0, (size_t)kNV * sizeof(int), stream);
  (void)hipMemsetAsync(part, 0, (size_t)kB * 16 * 256 * sizeof(float), stream);
  (void)hipMemsetAsync(x1q + (size_t)kNV * 128, 0, 128, stream);   // zero rows
  (void)hipMemsetAsync(x2q + (size_t)kNV * 256, 0, 256, stream);

  // CSR build, degree-padded to multiples of 4
  count_deg_kernel<<<(kNE + 255) / 256, 256, 0, stream>>>(edges, deg);
  block_sum_kernel<<<kScanBlocks, 256, 0, stream>>>(deg, bsum);
  scan_bsum_kernel<<<1, 1024, 0, stream>>>(bsum, boff, rowptr + kNV);
  write_rowptr_kernel<<<kScanBlocks, 256, 0, stream>>>(deg, boff, rowptr, cursor, rowinfo);
  fill_adj_kernel<<<(kNE + 255) / 256, 256, 0, stream>>>(edges, cursor, adj);
  pad_adj_kernel<<<(kNV + 255) / 256, 256, 0, stream>>>(deg, rowptr, adj);

  // Weight prep: bf16 swizzle (W1 half used) + fp8 W0 frags
  prep_wswz_kernel<<<32, 256, 0, stream>>>(g1w0, g1w1, ws1, 128);
  prep_wswz_kernel<<<64, 256, 0, stream>>>(g2w0, g2w1, ws2, 256);
  prep_wswz_fp8_kernel<<<16, 256, 0, stream>>>(g1w0, ws1q, 128);
  prep_wswz_fp8_kernel<<<32, 256, 0, stream>>>(g2w0, ws2q, 256);

  // GCN layers (activations fp8 end-to-end; aggregation bf16)
  gcn_layer0_kernel<<<kNV / 256, 256, 0, stream>>>(verts, rowptr, deg, adj,
                                                   g0w0, g0b0, g0w1, g0b1, x1q);
  gcn_l1_kernel<<<kNV / 32, 256, 0, stream>>>(
      x1q, rowinfo, adj, ws1, ws1q, g1b0, g1b1, x2q);
  gcn_l2pool_kernel<<<dim3((kV + 31) / 32, kB), 256, 0, stream>>>(
      x2q, rowinfo, adj, ws2, ws2q, g2b0, g2b1, part);
  pool_reduce_kernel<<<kB, 256, 0, stream>>>(part, pooled);

  // MLP head
  fc1_kernel<<<dim3(kB, 4), 256, 0, stream>>>(pooled, fc1w, fc1b, h);
  fc2_kernel<<<kB * 10, 64, 0, stream>>>(h, fc2w, fc2b, outp);
}

// Round 15
// 407.202 us; speedup vs baseline: 1.0487x; 1.0487x over previous
//
#include <hip/hip_runtime.h>
#include <hip/hip_bf16.h>

typedef __attribute__((ext_vector_type(8))) short short8;
typedef __attribute__((ext_vector_type(4))) float f32x4;
typedef __attribute__((ext_vector_type(2))) float floatx2;
typedef __attribute__((ext_vector_type(4))) unsigned uintx4;
typedef __attribute__((ext_vector_type(2))) unsigned uintx2;

namespace {

constexpr int kNV = 160000;
constexpr int kNE = 480000;
constexpr int kB  = 16;
constexpr int kV  = 10000;
constexpr int kScanBlocks = kNV / 256;  // 625, exact
constexpr int kMaxAdjPad = 2 * kNE + 3 * kNV;  // 1,440,000 worst case

__device__ inline unsigned short f2b(float f) {  // fp32 -> bf16 RNE
  unsigned u = __float_as_uint(f);
  unsigned r = u + 0x7fffu + ((u >> 16) & 1u);
  return (unsigned short)(r >> 16);
}
__device__ inline unsigned pk2(float lo, float hi) {
  return ((unsigned)f2b(hi) << 16) | (unsigned)f2b(lo);
}
// fp32 -> OCP e4m3 via HW converter (RNE, saturating)
__device__ inline unsigned char f2q(float f) {
  int r = __builtin_amdgcn_cvt_pk_fp8_f32(f, 0.f, 0, false);
  return (unsigned char)(r & 0xff);
}

// ---------------- CSR build (degree-padded to multiples of 4) ----------------

__global__ __launch_bounds__(256) void count_deg_kernel(const int2* __restrict__ edges,
                                                        int* __restrict__ deg) {
  int i = blockIdx.x * 256 + threadIdx.x;
  if (i < kNE) {
    int2 e = edges[i];
    atomicAdd(&deg[e.x], 1);
    atomicAdd(&deg[e.y], 1);
  }
}

__global__ __launch_bounds__(256) void block_sum_kernel(const int* __restrict__ deg,
                                                        int* __restrict__ bsum) {
  const int tid = threadIdx.x;
  int v = (deg[blockIdx.x * 256 + tid] + 3) & ~3;
  for (int off = 32; off > 0; off >>= 1) v += __shfl_down(v, off);
  __shared__ int ws[4];
  if ((tid & 63) == 0) ws[tid >> 6] = v;
  __syncthreads();
  if (tid == 0) bsum[blockIdx.x] = ws[0] + ws[1] + ws[2] + ws[3];
}

__global__ __launch_bounds__(1024) void scan_bsum_kernel(const int* __restrict__ bsum,
                                                         int* __restrict__ boff,
                                                         int* __restrict__ total_out) {
  __shared__ int s[1024];
  const int t = threadIdx.x;
  int v = (t < kScanBlocks) ? bsum[t] : 0;
  s[t] = v;
  __syncthreads();
  for (int off = 1; off < 1024; off <<= 1) {
    int u = (t >= off) ? s[t - off] : 0;
    __syncthreads();
    s[t] += u;
    __syncthreads();
  }
  if (t < kScanBlocks) boff[t] = s[t] - v;
  if (t == kScanBlocks - 1) total_out[0] = s[t];
}

// Pass 3: rowptr/cursor + packed rowinfo {beg/4, (deg<<8)|nq}.
__global__ __launch_bounds__(256) void write_rowptr_kernel(const int* __restrict__ deg,
                                                           const int* __restrict__ boff,
                                                           int* __restrict__ rowptr,
                                                           int* __restrict__ cursor,
                                                           int2* __restrict__ rowinfo) {
  __shared__ int s[256];
  const int tid = threadIdx.x;
  const int i = blockIdx.x * 256 + tid;
  const int d = deg[i];
  int v = (d + 3) & ~3;
  s[tid] = v;
  __syncthreads();
  for (int off = 1; off < 256; off <<= 1) {
    int u = (tid >= off) ? s[tid - off] : 0;
    __syncthreads();
    s[tid] += u;
    __syncthreads();
  }
  int excl = s[tid] - v + boff[blockIdx.x];
  rowptr[i] = excl;
  cursor[i] = excl;
  rowinfo[i] = make_int2(excl >> 2, (d << 8) | (v >> 2));
}

__global__ __launch_bounds__(256) void fill_adj_kernel(const int2* __restrict__ edges,
                                                       int* __restrict__ cursor,
                                                       int* __restrict__ adj) {
  int i = blockIdx.x * 256 + threadIdx.x;
  if (i < kNE) {
    int2 e = edges[i];
    int p = atomicAdd(&cursor[e.x], 1);
    adj[p] = e.y;
    int q = atomicAdd(&cursor[e.y], 1);
    adj[q] = e.x;
  }
}

__global__ __launch_bounds__(256) void pad_adj_kernel(const int* __restrict__ deg,
                                                      const int* __restrict__ rowptr,
                                                      int* __restrict__ adj) {
  int v = blockIdx.x * 256 + threadIdx.x;
  if (v < kNV) {
    int e = rowptr[v] + deg[v];
    int e2 = rowptr[v + 1];
    for (int p = e; p < e2; ++p) adj[p] = kNV;
  }
}

// ------- Weight prep (bf16): MFMA-fragment-swizzled concat [W0|W1] ---------

__global__ __launch_bounds__(256) void prep_wswz_kernel(const float* __restrict__ w0,
                                                        const float* __restrict__ w1,
                                                        unsigned short* __restrict__ dst,
                                                        int din) {
  const int K = 2 * din;
  const int total = (K / 32) * 16 * 64;
  int g = blockIdx.x * 256 + threadIdx.x;
  if (g >= total) return;
  int lane = g & 63;
  int cb = (g >> 6) & 15;
  int s = g >> 10;
  int ch = cb * 16 + (lane & 15);
  int kb = s * 32 + (lane >> 4) * 8;
  unsigned short v[8];
#pragma unroll
  for (int j = 0; j < 8; ++j) {
    int k = kb + j;
    float f = (k < din) ? w0[(size_t)ch * din + k] : w1[(size_t)ch * din + (k - din)];
    v[j] = f2b(f);
  }
  uint4 pk;
  pk.x = (unsigned)v[0] | ((unsigned)v[1] << 16);
  pk.y = (unsigned)v[2] | ((unsigned)v[3] << 16);
  pk.z = (unsigned)v[4] | ((unsigned)v[5] << 16);
  pk.w = (unsigned)v[6] | ((unsigned)v[7] << 16);
  *(uint4*)(dst + (size_t)g * 8) = pk;
}

// ------- Weight prep (fp8): W0 half as fp8 B-frags, same fragment layout ----

__global__ __launch_bounds__(256) void prep_wswz_fp8_kernel(const float* __restrict__ w0,
                                                            unsigned char* __restrict__ dst,
                                                            int din) {
  const int total = (din / 32) * 16 * 64;
  int g = blockIdx.x * 256 + threadIdx.x;
  if (g >= total) return;
  int lane = g & 63;
  int cb = (g >> 6) & 15;
  int s = g >> 10;
  int ch = cb * 16 + (lane & 15);
  int kb = s * 32 + (lane >> 4) * 8;
  float f[8];
#pragma unroll
  for (int j = 0; j < 8; ++j) f[j] = w0[(size_t)ch * din + kb + j];
  int r0 = 0, r1 = 0;
  r0 = __builtin_amdgcn_cvt_pk_fp8_f32(f[0], f[1], r0, false);
  r0 = __builtin_amdgcn_cvt_pk_fp8_f32(f[2], f[3], r0, true);
  r1 = __builtin_amdgcn_cvt_pk_fp8_f32(f[4], f[5], r1, false);
  r1 = __builtin_amdgcn_cvt_pk_fp8_f32(f[6], f[7], r1, true);
  uintx2 pk;
  pk.x = (unsigned)r0;
  pk.y = (unsigned)r1;
  *(uintx2*)(dst + (size_t)g * 8) = pk;
}

// ------ Layer 0: din=3 -> dout=128; emits fp8 x1q only (coalesced) ----------

__global__ __launch_bounds__(256) void gcn_layer0_kernel(
    const float* __restrict__ x, const int* __restrict__ rowptr,
    const int* __restrict__ deg, const int* __restrict__ adj,
    const float* __restrict__ w0, const float* __restrict__ b0,
    const float* __restrict__ w1, const float* __restrict__ b1,
    unsigned char* __restrict__ yq) {
  constexpr int TM = 256, DOUT = 128;
  __shared__ __align__(16) float xa[TM][8];  // [0..2] self, [3..5] agg, [6] deg
  const int v0 = blockIdx.x * TM;
  const int tid = threadIdx.x;

  {
    const int v = v0 + tid;
    const float s0 = x[(size_t)v * 3 + 0];
    const float s1 = x[(size_t)v * 3 + 1];
    const float s2 = x[(size_t)v * 3 + 2];
    const int beg = rowptr[v];
    const int n = deg[v];
    float a0 = 0.f, a1 = 0.f, a2 = 0.f;
    int j = beg;
    const int e = beg + n;
    for (; j + 4 <= e; j += 4) {
      int u0 = adj[j], u1 = adj[j + 1], u2 = adj[j + 2], u3 = adj[j + 3];
      float p0 = x[(size_t)u0 * 3], p1 = x[(size_t)u0 * 3 + 1], p2 = x[(size_t)u0 * 3 + 2];
      float q0 = x[(size_t)u1 * 3], q1 = x[(size_t)u1 * 3 + 1], q2 = x[(size_t)u1 * 3 + 2];
      float r0 = x[(size_t)u2 * 3], r1 = x[(size_t)u2 * 3 + 1], r2 = x[(size_t)u2 * 3 + 2];
      float t0 = x[(size_t)u3 * 3], t1 = x[(size_t)u3 * 3 + 1], t2 = x[(size_t)u3 * 3 + 2];
      a0 += (p0 + q0) + (r0 + t0);
      a1 += (p1 + q1) + (r1 + t1);
      a2 += (p2 + q2) + (r2 + t2);
    }
    for (; j < e; ++j) {
      int u = adj[j];
      a0 += x[(size_t)u * 3 + 0];
      a1 += x[(size_t)u * 3 + 1];
      a2 += x[(size_t)u * 3 + 2];
    }
    xa[tid][0] = s0;
    xa[tid][1] = s1;
    xa[tid][2] = s2;
    xa[tid][3] = a0;
    xa[tid][4] = a1;
    xa[tid][5] = a2;
    xa[tid][6] = (float)n;
    xa[tid][7] = 0.f;
  }
  __syncthreads();

  const int o = tid & 127;
  const int half = tid >> 7;
  const float w00 = w0[o * 3], w01 = w0[o * 3 + 1], w02 = w0[o * 3 + 2];
  const float w10 = w1[o * 3], w11 = w1[o * 3 + 1], w12 = w1[o * 3 + 2];
  const float bb0 = b0[o], bb1 = b1[o];
  for (int m = half; m < TM; m += 2) {
    float4 lo = *(const float4*)&xa[m][0];
    float4 hi = *(const float4*)&xa[m][4];
    float r = bb0 + hi.z * bb1
            + lo.x * w00 + lo.y * w01 + lo.z * w02
            + lo.w * w10 + hi.x * w11 + hi.y * w12;
    yq[(size_t)(v0 + m) * DOUT + o] = f2q(fmaxf(r, 0.f));
  }
}

// ---------------- Fused GCN layer via MFMA (fp8 self+gather) ----------------
// Gather: dual-row half-wave pairs, PER-PAIR index loads with iB one quad
// ahead (round-13 measured-best; round-14's cross-pair pipeline spilled to
// scratch: WRITE 97->243 MB). rowinfo packs {beg/4, deg<<8|nq}: one 8B load
// replaces 3 dependent index-path loads. Pass 0: fp8_fp8 MFMA. Pass 1: bf16
// MFMA on LDS agg tile. l1 output: fp8 via swizzled LDS pack.

template <int DIN, bool POOL>
__device__ __forceinline__ void gcn_mfma_body(
    const unsigned char* __restrict__ xq,
    const int2* __restrict__ rowinfo,
    const int* __restrict__ adj, const unsigned short* __restrict__ wswz,
    const unsigned char* __restrict__ wq,
    const float* __restrict__ b0, const float* __restrict__ b1,
    void* __restrict__ out) {
  constexpr int TM = 32;
  constexpr int ROWB = DIN * 2;  // bytes per LDS agg row (bf16)
  __shared__ __align__(16) char lds[TM * ROWB];
  __shared__ float degs_s[TM];

  const int tid = threadIdx.x;
  const int lane = tid & 63;
  const int wave = tid >> 6;
  const int half = lane >> 5;  // row-pair selector
  const int hl = lane & 31;    // position within row

  int v0, valid, batch;
  if constexpr (POOL) {
    batch = blockIdx.y;
    v0 = batch * kV + blockIdx.x * TM;
    valid = min(TM, kV - (int)blockIdx.x * TM);
  } else {
    batch = 0;
    v0 = blockIdx.x * TM;
    valid = TM;
  }

  auto swz = [&](int row, int off) { return row * ROWB + (off ^ ((row & 7) << 4)); };

  const int4* adjq = reinterpret_cast<const int4*>(adj);
  const int4 Z4 = make_int4(kNV, kNV, kNV, kNV);

  // ---- gather: 4 dual-row pairs per wave, per-pair index loads ----
#pragma unroll
  for (int pr = 0; pr < 4; ++pr) {
    const int m = wave * 8 + pr * 2 + half;
    const bool live = m < valid;
    int2 ri = rowinfo[live ? (v0 + m) : v0];
    const int q0 = ri.x;
    const int nq = live ? (ri.y & 0xff) : 0;
    if (hl == 0) degs_s[m] = live ? (float)(ri.y >> 8) : 0.f;
    const int nqo = __shfl_xor(nq, 32);
    const int nqmax = max(nq, nqo);

    if constexpr (DIN == 256) {
      const uintx2* xr = reinterpret_cast<const uintx2*>(xq);  // row = 32 uintx2
      float r0 = 0, r1 = 0, r2 = 0, r3 = 0, r4 = 0, r5 = 0, r6 = 0, r7 = 0;
#define ACCQ8(c) do { \
    floatx2 f0 = __builtin_amdgcn_cvt_pk_f32_fp8((int)(c).x, false); \
    floatx2 f1 = __builtin_amdgcn_cvt_pk_f32_fp8((int)(c).x, true); \
    floatx2 f2 = __builtin_amdgcn_cvt_pk_f32_fp8((int)(c).y, false); \
    floatx2 f3 = __builtin_amdgcn_cvt_pk_f32_fp8((int)(c).y, true); \
    r0 += f0.x; r1 += f0.y; r2 += f1.x; r3 += f1.y; \
    r4 += f2.x; r5 += f2.y; r6 += f3.x; r7 += f3.y; } while (0)
      if (nqmax > 0) {
        int4 iA = (nq > 0) ? adjq[q0] : Z4;
        int4 iB = (nq > 1) ? adjq[q0 + 1] : Z4;
        uintx2 c0 = xr[(size_t)iA.x * 32 + hl];
        uintx2 c1 = xr[(size_t)iA.y * 32 + hl];
        uintx2 c2 = xr[(size_t)iA.z * 32 + hl];
        uintx2 c3 = xr[(size_t)iA.w * 32 + hl];
        for (int t = 1; t < nqmax; ++t) {
          uintx2 n0 = xr[(size_t)iB.x * 32 + hl];
          uintx2 n1 = xr[(size_t)iB.y * 32 + hl];
          uintx2 n2 = xr[(size_t)iB.z * 32 + hl];
          uintx2 n3 = xr[(size_t)iB.w * 32 + hl];
          iB = (t + 1 < nq) ? adjq[q0 + t + 1] : Z4;
          ACCQ8(c0); ACCQ8(c1); ACCQ8(c2); ACCQ8(c3);
          c0 = n0; c1 = n1; c2 = n2; c3 = n3;
        }
        ACCQ8(c0); ACCQ8(c1); ACCQ8(c2); ACCQ8(c3);
      }
#undef ACCQ8
      uintx4 pk;
      pk.x = pk2(r0, r1);
      pk.y = pk2(r2, r3);
      pk.z = pk2(r4, r5);
      pk.w = pk2(r6, r7);
      *(uintx4*)(lds + swz(m, hl * 16)) = pk;
    } else {  // DIN == 128
      const unsigned* xr = reinterpret_cast<const unsigned*>(xq);  // row = 32 uints
      float r0 = 0, r1 = 0, r2 = 0, r3 = 0;
#define ACCQ4(c) do { \
    floatx2 f0 = __builtin_amdgcn_cvt_pk_f32_fp8((int)(c), false); \
    floatx2 f1 = __builtin_amdgcn_cvt_pk_f32_fp8((int)(c), true); \
    r0 += f0.x; r1 += f0.y; r2 += f1.x; r3 += f1.y; } while (0)
      if (nqmax > 0) {
        int4 iA = (nq > 0) ? adjq[q0] : Z4;
        int4 iB = (nq > 1) ? adjq[q0 + 1] : Z4;
        unsigned c0 = xr[(size_t)iA.x * 32 + hl];
        unsigned c1 = xr[(size_t)iA.y * 32 + hl];
        unsigned c2 = xr[(size_t)iA.z * 32 + hl];
        unsigned c3 = xr[(size_t)iA.w * 32 + hl];
        for (int t = 1; t < nqmax; ++t) {
          unsigned n0 = xr[(size_t)iB.x * 32 + hl];
          unsigned n1 = xr[(size_t)iB.y * 32 + hl];
          unsigned n2 = xr[(size_t)iB.z * 32 + hl];
          unsigned n3 = xr[(size_t)iB.w * 32 + hl];
          iB = (t + 1 < nq) ? adjq[q0 + t + 1] : Z4;
          ACCQ4(c0); ACCQ4(c1); ACCQ4(c2); ACCQ4(c3);
          c0 = n0; c1 = n1; c2 = n2; c3 = n3;
        }
        ACCQ4(c0); ACCQ4(c1); ACCQ4(c2); ACCQ4(c3);
      }
#undef ACCQ4
      uintx2 pk;
      pk.x = pk2(r0, r1);
      pk.y = pk2(r2, r3);
      *(uintx2*)(lds + swz(m, hl * 8)) = pk;
    }
  }

  // ---- MFMA: wave -> channels [wave*64, wave*64+64) ----
  const int col = lane & 15;
  const int kgrp = lane >> 4;
  const int cbw = wave * 4;  // channel-block base (16-ch blocks)
  f32x4 acc[2][4] = {};

  // pass 0: fp8 self rows from global + fp8 W0 frags (same frag k-layout)
  const long* wql = reinterpret_cast<const long*>(wq);
  for (int s = 0; s < DIN / 32; ++s) {
    const int ke = s * 32 + kgrp * 8;
    long a0 = 0, a1 = 0;
    if constexpr (POOL) {
      if (col < valid)      a0 = *(const long*)(xq + (size_t)(v0 + col) * DIN + ke);
      if (col + 16 < valid) a1 = *(const long*)(xq + (size_t)(v0 + col + 16) * DIN + ke);
    } else {
      a0 = *(const long*)(xq + (size_t)(v0 + col) * DIN + ke);
      a1 = *(const long*)(xq + (size_t)(v0 + col + 16) * DIN + ke);
    }
#pragma unroll
    for (int nf = 0; nf < 4; ++nf) {
      long bq = wql[((size_t)(s * 16 + cbw + nf)) * 64 + lane];
      acc[0][nf] = __builtin_amdgcn_mfma_f32_16x16x32_fp8_fp8(a0, bq, acc[0][nf], 0, 0, 0);
      acc[1][nf] = __builtin_amdgcn_mfma_f32_16x16x32_fp8_fp8(a1, bq, acc[1][nf], 0, 0, 0);
    }
  }

  __syncthreads();

  // pass 1: agg rows from LDS (bf16), W1 half of bf16 wswz (s2 + DIN/32)
  for (int s2 = 0; s2 < DIN / 32; ++s2) {
    const int kb = (s2 * 32 + kgrp * 8) * 2;
    short8 a0 = *(const short8*)(lds + swz(col, kb));
    short8 a1 = *(const short8*)(lds + swz(col + 16, kb));
    const unsigned short* wb =
        wswz + ((size_t)((DIN / 32 + s2) * 16 + cbw) * 64 + lane) * 8;
#pragma unroll
    for (int nf = 0; nf < 4; ++nf) {
      short8 bfrag = *(const short8*)(wb + (size_t)nf * 512);
      acc[0][nf] = __builtin_amdgcn_mfma_f32_16x16x32_bf16(a0, bfrag, acc[0][nf], 0, 0, 0);
      acc[1][nf] = __builtin_amdgcn_mfma_f32_16x16x32_bf16(a1, bfrag, acc[1][nf], 0, 0, 0);
    }
  }

  // ---- epilogue: C/D map col=lane&15, row=(lane>>4)*4+reg (+16 for mf=1) ----
  const int rb = kgrp * 4;
  const int obase = wave * 64;
  if constexpr (POOL) {
    float* part = (float*)out;  // [kB][16][256] partial slots
    const int slot = blockIdx.x & 15;
#pragma unroll
    for (int nf = 0; nf < 4; ++nf) {
      int o = obase + nf * 16 + col;
      float bb0 = b0[o], bb1 = b1[o];
      float s = 0.f;
#pragma unroll
      for (int mf = 0; mf < 2; ++mf)
#pragma unroll
        for (int j = 0; j < 4; ++j) {
          int row = mf * 16 + rb + j;
          if (row < valid)
            s += fmaxf(acc[mf][nf][j] + bb0 + degs_s[row] * bb1, 0.f);
        }
      s += __shfl_xor(s, 16);
      s += __shfl_xor(s, 32);
      if (lane < 16)
        atomicAdd(&part[((size_t)batch * 16 + slot) * 256 + o], s * (1.0f / (float)kV));
    }
  } else {
    // fp8 output: pack into (consumed) LDS agg tile with 16B XOR swizzle,
    // then stream as coalesced 16B stores (TM*ROWB == 32*256 for DIN=128).
    __syncthreads();  // all waves done reading agg tile
    unsigned char* packb = (unsigned char*)lds;
#pragma unroll
    for (int nf = 0; nf < 4; ++nf) {
      int o = obase + nf * 16 + col;
      float bb0 = b0[o], bb1 = b1[o];
#pragma unroll
      for (int mf = 0; mf < 2; ++mf)
#pragma unroll
        for (int j = 0; j < 4; ++j) {
          int row = mf * 16 + rb + j;
          float val = fmaxf(acc[mf][nf][j] + bb0 + degs_s[row] * bb1, 0.f);
          packb[row * 256 + (o ^ ((row & 15) << 4))] = f2q(val);
        }
    }
    __syncthreads();
    unsigned char* xqo = (unsigned char*)out;
    const int row = tid >> 3;        // 0..31
    const int o0 = (tid & 7) * 32;   // 32B per thread
    const int xsw = (row & 15) << 4;
    uintx4 d0 = *(const uintx4*)(lds + row * 256 + (o0 ^ xsw));
    uintx4 d1 = *(const uintx4*)(lds + row * 256 + ((o0 + 16) ^ xsw));
    *(uintx4*)(xqo + (size_t)(v0 + row) * 256 + o0) = d0;
    *(uintx4*)(xqo + (size_t)(v0 + row) * 256 + o0 + 16) = d1;
  }
}

__global__ __launch_bounds__(256, 8) void gcn_l1_kernel(
    const unsigned char* __restrict__ xq, const int2* __restrict__ rowinfo,
    const int* __restrict__ adj, const unsigned short* __restrict__ wswz,
    const unsigned char* __restrict__ wq,
    const float* __restrict__ b0, const float* __restrict__ b1,
    void* __restrict__ out) {
  gcn_mfma_body<128, false>(xq, rowinfo, adj, wswz, wq, b0, b1, out);
}

__global__ __launch_bounds__(256, 8) void gcn_l2pool_kernel(
    const unsigned char* __restrict__ xq, const int2* __restrict__ rowinfo,
    const int* __restrict__ adj, const unsigned short* __restrict__ wswz,
    const unsigned char* __restrict__ wq,
    const float* __restrict__ b0, const float* __restrict__ b1,
    void* __restrict__ out) {
  gcn_mfma_body<256, true>(xq, rowinfo, adj, wswz, wq, b0, b1, out);
}

// Sum the 16 partial slots per batch into pooled[b][o].
__global__ __launch_bounds__(256) void pool_reduce_kernel(const float* __restrict__ part,
                                                          float* __restrict__ pooled) {
  const int b = blockIdx.x;
  const int o = threadIdx.x;
  float s = 0.f;
#pragma unroll
  for (int k = 0; k < 16; ++k) s += part[((size_t)b * 16 + k) * 256 + o];
  pooled[b * 256 + o] = s;
}

// ---------------- MLP head ----------------

__global__ __launch_bounds__(256) void fc1_kernel(const float* __restrict__ pooled,
                                                  const float* __restrict__ w,
                                                  const float* __restrict__ b,
                                                  float* __restrict__ h) {
  __shared__ float ps[256];
  const int bb = blockIdx.x;
  const int o = blockIdx.y * 256 + threadIdx.x;
  ps[threadIdx.x] = pooled[bb * 256 + threadIdx.x];
  __syncthreads();
  const float4* wr = reinterpret_cast<const float4*>(w + (size_t)o * 256);
  float acc = b[o];
  for (int d4 = 0; d4 < 64; ++d4) {
    float4 wv = wr[d4];
    acc += ps[d4 * 4 + 0] * wv.x + ps[d4 * 4 + 1] * wv.y
         + ps[d4 * 4 + 2] * wv.z + ps[d4 * 4 + 3] * wv.w;
  }
  h[bb * 1024 + o] = fmaxf(acc, 0.f);
}

__global__ __launch_bounds__(64) void fc2_kernel(const float* __restrict__ h,
                                                 const float* __restrict__ w,
                                                 const float* __restrict__ b,
                                                 float* __restrict__ out) {
  const int t = blockIdx.x;  // 0..159
  const int bb = t / 10, c = t % 10;
  const int lane = threadIdx.x;
  const float* hr = h + bb * 1024;
  const float* wr = w + c * 1024;
  float acc = 0.f;
#pragma unroll
  for (int k = 0; k < 16; ++k) acc += hr[k * 64 + lane] * wr[k * 64 + lane];
#pragma unroll
  for (int off = 32; off > 0; off >>= 1) acc += __shfl_xor(acc, off);
  if (lane == 0) out[t] = acc + b[c];
}

}  // namespace

extern "C" void kernel_launch(void* const* d_in, const int* in_sizes, int n_in,
                              void* d_out, int out_size, void* d_ws, size_t ws_size,
                              hipStream_t stream) {
  const float* verts = (const float*)d_in[0];
  const int2*  edges = (const int2*)d_in[1];
  const float* g0w0 = (const float*)d_in[2];
  const float* g0b0 = (const float*)d_in[3];
  const float* g0w1 = (const float*)d_in[4];
  const float* g0b1 = (const float*)d_in[5];
  const float* g1w0 = (const float*)d_in[6];
  const float* g1b0 = (const float*)d_in[7];
  const float* g1w1 = (const float*)d_in[8];
  const float* g1b1 = (const float*)d_in[9];
  const float* g2w0 = (const float*)d_in[10];
  const float* g2b0 = (const float*)d_in[11];
  const float* g2w1 = (const float*)d_in[12];
  const float* g2b1 = (const float*)d_in[13];
  const float* fc1w = (const float*)d_in[14];
  const float* fc1b = (const float*)d_in[15];
  const float* fc2w = (const float*)d_in[16];
  const float* fc2b = (const float*)d_in[17];
  float* outp = (float*)d_out;

  char* p = (char*)d_ws;
  auto alloc = [&](size_t bytes) {
    char* r = p;
    p += (bytes + 255) & ~(size_t)255;
    return r;
  };
  unsigned char*  x1q  = (unsigned char*)alloc((size_t)(kNV + 1) * 128);   // fp8, +zero row
  unsigned char*  x2q  = (unsigned char*)alloc((size_t)(kNV + 1) * 256);   // fp8, +zero row
  unsigned short* ws1  = (unsigned short*)alloc((size_t)256 * 256 * 2);    // bf16 [W0|W1]
  unsigned short* ws2  = (unsigned short*)alloc((size_t)256 * 512 * 2);
  unsigned char*  ws1q = (unsigned char*)alloc((size_t)(128 / 32) * 16 * 64 * 8);  // fp8 W0
  unsigned char*  ws2q = (unsigned char*)alloc((size_t)(256 / 32) * 16 * 64 * 8);
  int*   deg    = (int*)alloc((size_t)kNV * sizeof(int));
  int*   rowptr = (int*)alloc((size_t)(kNV + 1) * sizeof(int));
  int*   cursor = (int*)alloc((size_t)kNV * sizeof(int));
  int2*  rowinfo = (int2*)alloc((size_t)kNV * sizeof(int2));
  int*   adj    = (int*)alloc((size_t)kMaxAdjPad * sizeof(int));
  int*   bsum   = (int*)alloc((size_t)kScanBlocks * sizeof(int));
  int*   boff   = (int*)alloc((size_t)kScanBlocks * sizeof(int));
  float* part   = (float*)alloc((size_t)kB * 16 * 256 * sizeof(float));
  float* pooled = (float*)alloc((size_t)kB * 256 * sizeof(float));
  float* h      = (float*)alloc((size_t)kB * 1024 * sizeof(float));

  (void)hipMemsetAsync(deg, 0, (size_t)kNV * sizeof(int), stream);
  (void)hipMemsetAsync(part, 0, (size_t)kB * 16 * 256 * sizeof(float), stream);
  (void)hipMemsetAsync(x1q + (size_t)kNV * 128, 0, 128, stream);   // zero rows
  (void)hipMemsetAsync(x2q + (size_t)kNV * 256, 0, 256, stream);

  // CSR build, degree-padded to multiples of 4
  count_deg_kernel<<<(kNE + 255) / 256, 256, 0, stream>>>(edges, deg);
  block_sum_kernel<<<kScanBlocks, 256, 0, stream>>>(deg, bsum);
  scan_bsum_kernel<<<1, 1024, 0, stream>>>(bsum, boff, rowptr + kNV);
  write_rowptr_kernel<<<kScanBlocks, 256, 0, stream>>>(deg, boff, rowptr, cursor, rowinfo);
  fill_adj_kernel<<<(kNE + 255) / 256, 256, 0, stream>>>(edges, cursor, adj);
  pad_adj_kernel<<<(kNV + 255) / 256, 256, 0, stream>>>(deg, rowptr, adj);

  // Weight prep: bf16 swizzle (W1 half used) + fp8 W0 frags
  prep_wswz_kernel<<<32, 256, 0, stream>>>(g1w0, g1w1, ws1, 128);
  prep_wswz_kernel<<<64, 256, 0, stream>>>(g2w0, g2w1, ws2, 256);
  prep_wswz_fp8_kernel<<<16, 256, 0, stream>>>(g1w0, ws1q, 128);
  prep_wswz_fp8_kernel<<<32, 256, 0, stream>>>(g2w0, ws2q, 256);

  // GCN layers (activations fp8 end-to-end; aggregation bf16)
  gcn_layer0_kernel<<<kNV / 256, 256, 0, stream>>>(verts, rowptr, deg, adj,
                                                   g0w0, g0b0, g0w1, g0b1, x1q);
  gcn_l1_kernel<<<kNV / 32, 256, 0, stream>>>(
      x1q, rowinfo, adj, ws1, ws1q, g1b0, g1b1, x2q);
  gcn_l2pool_kernel<<<dim3((kV + 31) / 32, kB), 256, 0, stream>>>(
      x2q, rowinfo, adj, ws2, ws2q, g2b0, g2b1, part);
  pool_reduce_kernel<<<kB, 256, 0, stream>>>(part, pooled);

  // MLP head
  fc1_kernel<<<dim3(kB, 4), 256, 0, stream>>>(pooled, fc1w, fc1b, h);
  fc2_kernel<<<kB * 10, 64, 0, stream>>>(h, fc2w, fc2b, outp);
}